// Round 11
// baseline (1232.588 us; speedup 1.0000x reference)
//
#include <hip/hip_runtime.h>
#include <cstdint>

// Problem constants: B=2, T=2048, C=1024, H=16, D=64, TOP_K=256
// feat_keep = ceil(D*min(TOP_K,T)/T) = ceil(64*256/2048) = 8
constexpr int Tn = 2048;
constexpr int Cn = 1024;
constexpr int Mn = 4096;          // B*T
constexpr int KKEEP = 256;        // row-wise top-k
constexpr int FKEEP = 8;          // feature top-k
constexpr unsigned U_NEG_INF = 0x007FFFFFu;  // umap(-inf)

// Score row layout in LDS: 64 chunks of 33 words (32 cols + 1 pad).
// Striped access col = j*64+lane -> addr = j*66 + lane_base: <=2-way banks.
constexpr int SC_ROW = 64 * 33;   // 2112 words per query row
constexpr int NW     = 4;         // waves (query rows) per attn block
__device__ __forceinline__ int sc_addr(int col) { return (col >> 5) * 33 + (col & 31); }

// Order-preserving fp32 -> uint32 map (monotonic incl. +-inf; no NaNs here).
__device__ __forceinline__ unsigned umap(float f) {
    unsigned b = __float_as_uint(f);
    return (b & 0x80000000u) ? ~b : (b | 0x80000000u);
}
__device__ __forceinline__ float uunmap(unsigned u) {
    return __uint_as_float((u & 0x80000000u) ? (u ^ 0x80000000u) : ~u);
}

// fp32 -> bf16 (RNE).
__device__ __forceinline__ unsigned short f2bf(float f) {
    unsigned u = __float_as_uint(f);
    u += 0x7FFFu + ((u >> 16) & 1u);
    return (unsigned short)(u >> 16);
}
// Split fp32 into hi+lo bf16 pair (by value: ext-vector elems can't bind to
// non-const refs — R7).  x ~= hi + lo, ~17-bit effective mantissa.
struct bfpair { unsigned short h, l; };
__device__ __forceinline__ bfpair split_bf16(float x) {
    bfpair r;
    r.h = f2bf(x);
    r.l = f2bf(x - __uint_as_float((unsigned)r.h << 16));
    return r;
}

// Wave-uniform broadcasts on the SALU path (NOT ds_bpermute / LDS pipe).
__device__ __forceinline__ int   rli(int v, int l)   { return __builtin_amdgcn_readlane(v, l); }
__device__ __forceinline__ float rlf(float v, int l) {
    return __int_as_float(__builtin_amdgcn_readlane(__float_as_int(v), l));
}

typedef __attribute__((ext_vector_type(8))) short          short8v;  // 8 bf16
typedef __attribute__((ext_vector_type(8))) unsigned short ushort8v;
typedef __attribute__((ext_vector_type(4))) float          f32x4;    // MFMA acc

// ---------------------------------------------------------------------------
// Split-bf16 MFMA GEMM ("3xBF16"): O[m][n] = sum_k A[m][k] * W[n][k],
// fp32 in/out at ~fp32 accuracy (R8: reproduces the fp32 canary absmax
// exactly).  acc += Ah*Bh + Ah*Bl + Al*Bh (lo*lo ~2^-18, dropped).
// 128x128 tile, BK=32, 256 thr = 4 waves (2x2), 4x4 16x16x32 MFMAs per wave.
// LDS rows padded to 40 ushorts (80 B stride -> <=2-way banks).
// blockIdx.z selects W/O (z=3 for QKV, z=1 for out-proj).
// ---------------------------------------------------------------------------
__global__ __launch_bounds__(256, 2)
void gemm_nt_3bf16(const float* __restrict__ A,
                   const float* __restrict__ W0, const float* __restrict__ W1,
                   const float* __restrict__ W2,
                   float* __restrict__ O0, float* __restrict__ O1,
                   float* __restrict__ O2)
{
    const float* Wm = (blockIdx.z == 0) ? W0 : (blockIdx.z == 1 ? W1 : W2);
    float*       O  = (blockIdx.z == 0) ? O0 : (blockIdx.z == 1 ? O1 : O2);

    __shared__ unsigned short Ah[128][40], Al[128][40];   // 2 x 10240 B
    __shared__ unsigned short Bh[128][40], Bl[128][40];   // 2 x 10240 B

    const int tid  = threadIdx.x;
    const int lane = tid & 63;
    const int wv   = tid >> 6;               // 0..3
    const int wm   = wv >> 1, wn = wv & 1;   // 2x2 wave grid
    const int fm   = lane & 15;              // fragment row/col
    const int fq   = lane >> 4;              // k-quad
    const int m0   = blockIdx.y * 128;
    const int n0   = blockIdx.x * 128;

    f32x4 acc[4][4] = {};

    for (int k0 = 0; k0 < Cn; k0 += 32) {
        __syncthreads();
        // stage 128 rows x 32 k of A and W, split hi/lo.  512 8-elem chunks
        // per matrix; 2 per thread per matrix.
#pragma unroll
        for (int r = 0; r < 2; ++r) {
            const int idx = tid + r * 256;
            const int row = idx >> 2, c8 = (idx & 3) * 8;
            {
                const float* s = &A[(size_t)(m0 + row) * Cn + k0 + c8];
                const float4 x0 = *(const float4*)s, x1 = *(const float4*)(s + 4);
                ushort8v h, l;
                bfpair p;
                p = split_bf16(x0.x); h[0] = p.h; l[0] = p.l;
                p = split_bf16(x0.y); h[1] = p.h; l[1] = p.l;
                p = split_bf16(x0.z); h[2] = p.h; l[2] = p.l;
                p = split_bf16(x0.w); h[3] = p.h; l[3] = p.l;
                p = split_bf16(x1.x); h[4] = p.h; l[4] = p.l;
                p = split_bf16(x1.y); h[5] = p.h; l[5] = p.l;
                p = split_bf16(x1.z); h[6] = p.h; l[6] = p.l;
                p = split_bf16(x1.w); h[7] = p.h; l[7] = p.l;
                *(ushort8v*)&Ah[row][c8] = h;
                *(ushort8v*)&Al[row][c8] = l;
            }
            {
                const float* s = &Wm[(size_t)(n0 + row) * Cn + k0 + c8];
                const float4 x0 = *(const float4*)s, x1 = *(const float4*)(s + 4);
                ushort8v h, l;
                bfpair p;
                p = split_bf16(x0.x); h[0] = p.h; l[0] = p.l;
                p = split_bf16(x0.y); h[1] = p.h; l[1] = p.l;
                p = split_bf16(x0.z); h[2] = p.h; l[2] = p.l;
                p = split_bf16(x0.w); h[3] = p.h; l[3] = p.l;
                p = split_bf16(x1.x); h[4] = p.h; l[4] = p.l;
                p = split_bf16(x1.y); h[5] = p.h; l[5] = p.l;
                p = split_bf16(x1.z); h[6] = p.h; l[6] = p.l;
                p = split_bf16(x1.w); h[7] = p.h; l[7] = p.l;
                *(ushort8v*)&Bh[row][c8] = h;
                *(ushort8v*)&Bl[row][c8] = l;
            }
        }
        __syncthreads();

        short8v ah[4], al[4], bh[4], bl[4];
#pragma unroll
        for (int ti = 0; ti < 4; ++ti) {
            ah[ti] = *(const short8v*)&Ah[wm * 64 + ti * 16 + fm][fq * 8];
            al[ti] = *(const short8v*)&Al[wm * 64 + ti * 16 + fm][fq * 8];
            bh[ti] = *(const short8v*)&Bh[wn * 64 + ti * 16 + fm][fq * 8];
            bl[ti] = *(const short8v*)&Bl[wn * 64 + ti * 16 + fm][fq * 8];
        }
#pragma unroll
        for (int ti = 0; ti < 4; ++ti)
#pragma unroll
            for (int tj = 0; tj < 4; ++tj) {
                acc[ti][tj] = __builtin_amdgcn_mfma_f32_16x16x32_bf16(
                    ah[ti], bh[tj], acc[ti][tj], 0, 0, 0);
                acc[ti][tj] = __builtin_amdgcn_mfma_f32_16x16x32_bf16(
                    ah[ti], bl[tj], acc[ti][tj], 0, 0, 0);
                acc[ti][tj] = __builtin_amdgcn_mfma_f32_16x16x32_bf16(
                    al[ti], bh[tj], acc[ti][tj], 0, 0, 0);
            }
    }

#pragma unroll
    for (int ti = 0; ti < 4; ++ti)
#pragma unroll
        for (int tj = 0; tj < 4; ++tj)
#pragma unroll
            for (int r = 0; r < 4; ++r) {
                const int row = m0 + wm * 64 + ti * 16 + fq * 4 + r;
                const int col = n0 + wn * 64 + tj * 16 + fm;
                O[(size_t)row * Cn + col] = acc[ti][tj][r];
            }
}

// ---------------------------------------------------------------------------
// Feature sparsify for Q and V (in place): per 64-elem head vector keep
// |v| >= 8th-largest |v|.  One wave per vector; 2*65536 vectors.
// ---------------------------------------------------------------------------
__global__ __launch_bounds__(256)
void sparsify_topk(float* __restrict__ Q, float* __restrict__ V)
{
    const int wid  = (blockIdx.x * 256 + threadIdx.x) >> 6;  // global wave id
    const int lane = threadIdx.x & 63;
    const int tensor = wid >> 16;        // 0=Q, 1=V
    const int vec    = wid & 65535;
    float* base = tensor ? V : Q;

    const size_t off = (size_t)vec * 64 + lane;
    const float v = base[off];
    const float a = fabsf(v);

    int cnt = 0;   // # strictly greater than mine
#pragma unroll
    for (int j = 0; j < 64; ++j) {
        const float aj = __shfl(a, j);
        cnt += (aj > a) ? 1 : 0;
    }
    float cand = (cnt < FKEEP) ? a : 3.402823466e38f;
#pragma unroll
    for (int o = 32; o; o >>= 1) cand = fminf(cand, __shfl_xor(cand, o));
    base[off] = (a >= cand) ? v : 0.0f;
}

// ---------------------------------------------------------------------------
// K sparsify + transpose: K[b][t][h][d] -> KT[bh][d][t] (both coalesced via
// a 64x64 LDS tile).  Same top-8 filter as sparsify_topk (identical fp32
// values -> attn scores bit-identical to R10).  Grid (32 t-tiles, 32 bh).
// ---------------------------------------------------------------------------
__global__ __launch_bounds__(256)
void sparsify_k_t(const float* __restrict__ K, float* __restrict__ KT)
{
    __shared__ float tile[64][65];       // [t-row][d], pad 65

    const int tid = threadIdx.x;
    const int w = tid >> 6, lane = tid & 63;
    const int tt = blockIdx.x;           // t-tile 0..31
    const int bh = blockIdx.y;           // 0..31
    const int b = bh >> 4, h = bh & 15;
    const int t0 = tt * 64;

    // load 64 t-rows x 64 d, coalesced (each row = 256 B contiguous)
#pragma unroll
    for (int k = 0; k < 4; ++k) {
        const int c = tid + k * 256;     // 0..1023 float4-chunks
        const int row = c >> 4, off = (c & 15) * 4;
        const float4 v4 = *(const float4*)
            &K[(size_t)((b * Tn + t0 + row) * 16 + h) * 64 + off];
        tile[row][off + 0] = v4.x; tile[row][off + 1] = v4.y;
        tile[row][off + 2] = v4.z; tile[row][off + 3] = v4.w;
    }
    __syncthreads();

    // per-wave top-8 on t-rows w, w+4, ... (vector over d = lane)
#pragma unroll 1
    for (int r = w; r < 64; r += 4) {
        const float v = tile[r][lane];
        const float a = fabsf(v);
        int cnt = 0;
#pragma unroll
        for (int j = 0; j < 64; ++j) {
            const float aj = __shfl(a, j);
            cnt += (aj > a) ? 1 : 0;
        }
        float cand = (cnt < FKEEP) ? a : 3.402823466e38f;
#pragma unroll
        for (int o = 32; o; o >>= 1) cand = fminf(cand, __shfl_xor(cand, o));
        tile[r][lane] = (a >= cand) ? v : 0.0f;
    }
    __syncthreads();

    // store transposed: KT[(bh*64+d)*2048 + t0+lane], coalesced over t
#pragma unroll
    for (int k = 0; k < 16; ++k) {
        const int d = w + k * 4;
        KT[(((size_t)bh * 64 + d) << 11) + t0 + lane] = tile[lane][d];
    }
}

// ---------------------------------------------------------------------------
// Attention core, R11: ZERO barriers.  Score phase reads KT[bh][d][t]
// directly from global — coalesced 256 B per (feature, 64-col group) — no
// LDS K staging, no __syncthreads (R10: ~550 barrier-drains/CU in the score
// phase marched all 16 waves in lockstep).  Every phase is wave-private:
// own sc row, own hist row.  Block = 4 waves = 4 query rows; 37888 B LDS ->
// 4 blocks/CU; 16384 blocks for tail balancing.
// Scores bit-identical to R10 (same fp32 K values, same m-order fma).
// ---------------------------------------------------------------------------
__global__ __launch_bounds__(256, 4)
void attn_kernel(const float* __restrict__ Qm, const float* __restrict__ KTm,
                 const float* __restrict__ Vm, float* __restrict__ AO)
{
    extern __shared__ unsigned smem[];
    unsigned* sc   = smem;                   // NW*2112 words
    unsigned* hist = smem + NW * SC_ROW;     // NW*256 words (select + compact)

    const int tid  = threadIdx.x;
    const int w    = tid >> 6;
    const int lane = tid & 63;
    const int bh   = blockIdx.y;             // 0..31
    const int b    = bh >> 4;
    const int h    = bh & 15;
    const int t    = blockIdx.x * NW + w;
    const size_t rowoff = ((size_t)(b * Tn + t) << 10) + (h << 6);
    const size_t kvoff  = ((size_t)(b * Tn) << 10) + (h << 6);

    unsigned* myrow = sc + w * SC_ROW;
    const int lb = (lane >> 5) * 33 + (lane & 31);  // striped lane base

    // ---- init own score row (incl pads): wave-private, no barrier ----
#pragma unroll
    for (int i = 0; i < 33; ++i) myrow[i * 64 + lane] = U_NEG_INF;

    // ---- sparse q row in a register; nonzero feature mask (wave-uniform) ----
    const float q0  = Qm[rowoff + lane];
    const float qsc = q0 * 0.125f;                  // fold 1/sqrt(D)
    const unsigned long long nzm = __ballot(q0 != 0.0f);

    const int nj = (t >> 6) + 1;             // visible 64-col groups
    const float* ktb = KTm + ((size_t)bh << 17);    // [d][t] slice

    unsigned rowmax = 0u;
    // ---- score phase: coalesced KT reads, barrier-free ----
    for (int j = 0; j < nj; ++j) {
        const int col = (j << 6) + lane;
        float s = 0.0f;
        unsigned long long mm = nzm;
        while (mm) {                         // nnz (~8) iters, wave-uniform
            const int m = __builtin_ctzll(mm); mm &= mm - 1;
            const float qm = rlf(qsc, m);
            s += qm * ktb[((size_t)m << 11) + col];
        }
        const unsigned val = (col <= t) ? umap(s) : U_NEG_INF;
        myrow[j * 66 + lb] = val;
        rowmax = (val > rowmax) ? val : rowmax;
    }

#pragma unroll
    for (int o = 32; o; o >>= 1) {
        const unsigned m2 = __shfl_xor(rowmax, o);
        rowmax = (m2 > rowmax) ? m2 : rowmax;
    }
    const float fm = uunmap(rowmax);         // row max (finite: col 0 <= t)

    // ---- exact kth via radix-256 select over LDS (wave-local) ----
    unsigned cur = U_NEG_INF;                // rows t<256 keep everything
    if (t >= KKEEP) {
        unsigned* hrow = hist + w * 256;
        unsigned prefix = 0u, pmask = 0u;
        unsigned r = KKEEP;
#pragma unroll 1
        for (int level = 0; level < 4; ++level) {
            const int sh = 24 - 8 * level;
            hrow[lane] = 0; hrow[64 + lane] = 0; hrow[128 + lane] = 0; hrow[192 + lane] = 0;
            __asm__ volatile("s_waitcnt lgkmcnt(0)" ::: "memory");
#pragma unroll 1
            for (int j = 0; j < nj; ++j) {
                const int col = (j << 6) + lane;
                if (col <= t) {
                    const unsigned v = myrow[j * 66 + lb];
                    if ((v & pmask) == prefix)
                        atomicAdd(&hrow[(v >> sh) & 255u], 1u);
                }
            }
            __asm__ volatile("s_waitcnt lgkmcnt(0)" ::: "memory");
            const uint4 hv = *(const uint4*)&hrow[lane * 4];   // bins 4l..4l+3
            const unsigned ls = hv.x + hv.y + hv.z + hv.w;
            unsigned sfx = ls;                    // inclusive suffix over lanes
#pragma unroll
            for (int off = 1; off < 64; off <<= 1) {
                const unsigned tt2 = __shfl_down(sfx, off);
                if (lane + off < 64) sfx += tt2;
            }
            const unsigned excl = sfx - ls;       // lanes strictly above
            const unsigned c3 = excl + hv.w, c2 = c3 + hv.z,
                           c1 = c2 + hv.y,  c0 = c1 + hv.x;
            int bsel = -1; unsigned csel = 0, cnext = 0;
            if      (c3 >= r) { bsel = 4 * lane + 3; csel = c3; cnext = excl; }
            else if (c2 >= r) { bsel = 4 * lane + 2; csel = c2; cnext = c3; }
            else if (c1 >= r) { bsel = 4 * lane + 1; csel = c1; cnext = c2; }
            else if (c0 >= r) { bsel = 4 * lane + 0; csel = c0; cnext = c1; }
            int B = bsel;
#pragma unroll
            for (int off = 32; off; off >>= 1) {
                const int ob = __shfl_xor(B, off);
                B = (ob > B) ? ob : B;
            }
            const unsigned cB  = (unsigned)__shfl((int)csel,  B >> 2);
            const unsigned cB1 = (unsigned)__shfl((int)cnext, B >> 2);
            prefix |= (unsigned)B << sh;
            pmask  |= 255u << sh;
            if (cB == r || level == 3) { cur = prefix; break; }
            r -= cB1;                    // rank within bin B
        }
    }

    // ---- softmax over kept visible entries; write p back ----
    float ps = 0.0f;
#pragma unroll 1
    for (int j = 0; j < nj; ++j) {
        const int col = (j << 6) + lane;
        if (col <= t) {
            const unsigned uv = myrow[j * 66 + lb];
            const float pv = (uv >= cur) ? __expf(uunmap(uv) - fm) : 0.0f;
            myrow[j * 66 + lb] = __float_as_uint(pv);
            ps += pv;
        }
    }
#pragma unroll
    for (int o = 32; o; o >>= 1) ps += __shfl_xor(ps, o);
    const float inv = 1.0f / ps;         // ps >= 1 (row max is kept)

    // ---- compact kept cols into this wave's hist row (<=256) ----
    unsigned* ct = hist + w * 256;       // own row only: no cross-wave hazard
    int cnt = 0; bool ovf = false;
#pragma unroll 1
    for (int g = 0; g < nj; ++g) {
        const int col = (g << 6) + lane;
        const float pv = (col <= t) ? __uint_as_float(myrow[g * 66 + lb]) : 0.0f;
        const unsigned long long m = __ballot(pv > 0.0f);
        const int c = __popcll(m);
        if (cnt + c <= 256) {
            if (pv > 0.0f)
                ct[cnt + __popcll(m & ((1ull << lane) - 1ull))] = (unsigned)col;
        } else ovf = true;
        cnt += c;
    }

    float acc = 0.0f;
    const float* __restrict__ vcol = Vm + kvoff + lane;
    if (!ovf) {
        // lane l holds list entries blk*64+l; entries >= cnt: c=0, p=0.
        int   cR[4]; float pR[4];
#pragma unroll
        for (int blk = 0; blk < 4; ++blk) {
            const int idx = blk * 64 + lane;
            cR[blk] = (idx < cnt) ? (int)ct[idx] : 0;
            pR[blk] = (idx < cnt) ? __uint_as_float(myrow[sc_addr(cR[blk])]) : 0.0f;
        }
        // Broadcast via readlane (SALU), 4 independent loads per group.
        // NOTE: blk_p MUST be float (R9: `int blk_p` truncated all p to 0).
        auto do_blk = [&](int blk_c, float blk_p) {
#pragma unroll
            for (int j = 0; j < 64; j += 4) {
                const int   ca = rli(blk_c, j + 0), cb = rli(blk_c, j + 1);
                const int   cc = rli(blk_c, j + 2), cd = rli(blk_c, j + 3);
                const float pa = rlf(blk_p, j + 0), pb = rlf(blk_p, j + 1);
                const float pc = rlf(blk_p, j + 2), pd = rlf(blk_p, j + 3);
                const float va = vcol[(size_t)ca * Cn], vb = vcol[(size_t)cb * Cn];
                const float vc = vcol[(size_t)cc * Cn], vd = vcol[(size_t)cd * Cn];
                acc += pa * va; acc += pb * vb; acc += pc * vc; acc += pd * vd;
            }
        };
        do_blk(cR[0], pR[0]);
        if (cnt > 64)  do_blk(cR[1], pR[1]);
        if (cnt > 128) do_blk(cR[2], pR[2]);
        if (cnt > 192) do_blk(cR[3], pR[3]);
    } else {
        // tie-overflow fallback (rare): while(ballot) gather
#pragma unroll 1
        for (int g = 0; g < nj; ++g) {
            const int col = (g << 6) + lane;
            const float pv = (col <= t) ? __uint_as_float(myrow[g * 66 + lb]) : 0.0f;
            unsigned long long m = __ballot(pv > 0.0f);
            const int cb = g << 6;
            while (m) {
                const int l0 = __builtin_ctzll(m); m &= m - 1;
                const float w0 = __shfl(pv, l0);
                const float v0 = vcol[(size_t)(cb + l0) * Cn];
                float w1 = 0.0f, v1 = 0.0f;
                if (m) {
                    const int l1 = __builtin_ctzll(m); m &= m - 1;
                    w1 = __shfl(pv, l1);
                    v1 = vcol[(size_t)(cb + l1) * Cn];
                }
                acc += w0 * v0;
                acc += w1 * v1;
            }
        }
    }
    AO[rowoff + lane] = acc * inv;
}

// ---------------------------------------------------------------------------
extern "C" void kernel_launch(void* const* d_in, const int* in_sizes, int n_in,
                              void* d_out, int out_size, void* d_ws, size_t ws_size,
                              hipStream_t stream)
{
    const float* x  = (const float*)d_in[0];
    const float* Wq = (const float*)d_in[1];
    const float* Wk = (const float*)d_in[2];
    const float* Wv = (const float*)d_in[3];
    const float* Wo = (const float*)d_in[4];
    float* out = (float*)d_out;

    // 4 x 16.8 MB workspace buffers (same footprint as R10):
    //   buf0=Q, buf1=K-dense (dead after transpose; reused as AO),
    //   buf2=V, buf3=KT.
    float* Q  = (float*)d_ws;
    float* K  = Q + (size_t)Mn * Cn;
    float* V  = K + (size_t)Mn * Cn;
    float* KT = V + (size_t)Mn * Cn;
    float* AO = K;                       // alias: K-dense dead after step 3

    constexpr int ATTN_LDS = NW * (SC_ROW + 256) * 4;    // 37888 B
    static_assert(ATTN_LDS <= 65536, "LDS over default dynamic cap");

    // 1) Q/K/V projections (split-bf16 MFMA, ~fp32 accuracy)
    gemm_nt_3bf16<<<dim3(Cn / 128, Mn / 128, 3), 256, 0, stream>>>(
        x, Wq, Wk, Wv, Q, K, V);

    // 2) feature top-8 sparsification of Q and V, in place
    sparsify_topk<<<dim3(2 * 65536 / 4), 256, 0, stream>>>(Q, V);

    // 3) K sparsify + transpose -> KT[bh][d][t]
    sparsify_k_t<<<dim3(32, 32), 256, 0, stream>>>(K, KT);

    // 4) barrier-free sparse attention core -> AO in [B,T,C] layout
    attn_kernel<<<dim3(Tn / NW, 32), 256, ATTN_LDS, stream>>>(Q, KT, V, AO);

    // 5) output projection (split-bf16 MFMA)
    gemm_nt_3bf16<<<dim3(Cn / 128, Mn / 128, 1), 256, 0, stream>>>(
        AO, Wo, Wo, Wo, out, out, out);
}

// Round 12
// 989.992 us; speedup vs baseline: 1.2450x; 1.2450x over previous
//
#include <hip/hip_runtime.h>
#include <cstdint>

// Problem constants: B=2, T=2048, C=1024, H=16, D=64, TOP_K=256
// feat_keep = ceil(D*min(TOP_K,T)/T) = ceil(64*256/2048) = 8
constexpr int Tn = 2048;
constexpr int Cn = 1024;
constexpr int Mn = 4096;          // B*T
constexpr int KKEEP = 256;        // row-wise top-k
constexpr int FKEEP = 8;          // feature top-k
constexpr unsigned U_NEG_INF = 0x007FFFFFu;  // umap(-inf)

// Score row layout in LDS: 64 chunks of 33 words (32 cols + 1 pad).
// Striped access col = j*64+lane -> addr = j*66 + lane_base: <=2-way banks.
constexpr int SC_ROW = 64 * 33;   // 2112 words per query row
constexpr int NW     = 4;         // waves (query rows) per attn block
__device__ __forceinline__ int sc_addr(int col) { return (col >> 5) * 33 + (col & 31); }

// Order-preserving fp32 -> uint32 map (monotonic incl. +-inf; no NaNs here).
__device__ __forceinline__ unsigned umap(float f) {
    unsigned b = __float_as_uint(f);
    return (b & 0x80000000u) ? ~b : (b | 0x80000000u);
}
__device__ __forceinline__ float uunmap(unsigned u) {
    return __uint_as_float((u & 0x80000000u) ? (u ^ 0x80000000u) : ~u);
}

// fp32 -> bf16 (RNE).
__device__ __forceinline__ unsigned short f2bf(float f) {
    unsigned u = __float_as_uint(f);
    u += 0x7FFFu + ((u >> 16) & 1u);
    return (unsigned short)(u >> 16);
}
// Split fp32 into hi+lo bf16 pair (by value: ext-vector elems can't bind to
// non-const refs — R7).  x ~= hi + lo, ~17-bit effective mantissa.
struct bfpair { unsigned short h, l; };
__device__ __forceinline__ bfpair split_bf16(float x) {
    bfpair r;
    r.h = f2bf(x);
    r.l = f2bf(x - __uint_as_float((unsigned)r.h << 16));
    return r;
}

// Wave-uniform broadcasts on the SALU path (NOT ds_bpermute / LDS pipe).
__device__ __forceinline__ int   rli(int v, int l)   { return __builtin_amdgcn_readlane(v, l); }
__device__ __forceinline__ float rlf(float v, int l) {
    return __int_as_float(__builtin_amdgcn_readlane(__float_as_int(v), l));
}

typedef __attribute__((ext_vector_type(8))) short          short8v;  // 8 bf16
typedef __attribute__((ext_vector_type(8))) unsigned short ushort8v;
typedef __attribute__((ext_vector_type(4))) float          f32x4;    // MFMA acc

// ---------------------------------------------------------------------------
// Split-bf16 MFMA GEMM ("3xBF16"): O[m][n] = sum_k A[m][k] * W[n][k],
// fp32 in/out at ~fp32 accuracy (R8: reproduces the fp32 canary absmax
// exactly).  acc += Ah*Bh + Ah*Bl + Al*Bh (lo*lo ~2^-18, dropped).
// 128x128 tile, BK=32, 256 thr = 4 waves (2x2), 4x4 16x16x32 MFMAs per wave.
// LDS rows padded to 40 ushorts (80 B stride -> <=2-way banks).
// blockIdx.z selects W/O (z=3 for QKV, z=1 for out-proj).
// ---------------------------------------------------------------------------
__global__ __launch_bounds__(256, 2)
void gemm_nt_3bf16(const float* __restrict__ A,
                   const float* __restrict__ W0, const float* __restrict__ W1,
                   const float* __restrict__ W2,
                   float* __restrict__ O0, float* __restrict__ O1,
                   float* __restrict__ O2)
{
    const float* Wm = (blockIdx.z == 0) ? W0 : (blockIdx.z == 1 ? W1 : W2);
    float*       O  = (blockIdx.z == 0) ? O0 : (blockIdx.z == 1 ? O1 : O2);

    __shared__ unsigned short Ah[128][40], Al[128][40];   // 2 x 10240 B
    __shared__ unsigned short Bh[128][40], Bl[128][40];   // 2 x 10240 B

    const int tid  = threadIdx.x;
    const int lane = tid & 63;
    const int wv   = tid >> 6;               // 0..3
    const int wm   = wv >> 1, wn = wv & 1;   // 2x2 wave grid
    const int fm   = lane & 15;              // fragment row/col
    const int fq   = lane >> 4;              // k-quad
    const int m0   = blockIdx.y * 128;
    const int n0   = blockIdx.x * 128;

    f32x4 acc[4][4] = {};

    for (int k0 = 0; k0 < Cn; k0 += 32) {
        __syncthreads();
        // stage 128 rows x 32 k of A and W, split hi/lo.  512 8-elem chunks
        // per matrix; 2 per thread per matrix.
#pragma unroll
        for (int r = 0; r < 2; ++r) {
            const int idx = tid + r * 256;
            const int row = idx >> 2, c8 = (idx & 3) * 8;
            {
                const float* s = &A[(size_t)(m0 + row) * Cn + k0 + c8];
                const float4 x0 = *(const float4*)s, x1 = *(const float4*)(s + 4);
                ushort8v h, l;
                bfpair p;
                p = split_bf16(x0.x); h[0] = p.h; l[0] = p.l;
                p = split_bf16(x0.y); h[1] = p.h; l[1] = p.l;
                p = split_bf16(x0.z); h[2] = p.h; l[2] = p.l;
                p = split_bf16(x0.w); h[3] = p.h; l[3] = p.l;
                p = split_bf16(x1.x); h[4] = p.h; l[4] = p.l;
                p = split_bf16(x1.y); h[5] = p.h; l[5] = p.l;
                p = split_bf16(x1.z); h[6] = p.h; l[6] = p.l;
                p = split_bf16(x1.w); h[7] = p.h; l[7] = p.l;
                *(ushort8v*)&Ah[row][c8] = h;
                *(ushort8v*)&Al[row][c8] = l;
            }
            {
                const float* s = &Wm[(size_t)(n0 + row) * Cn + k0 + c8];
                const float4 x0 = *(const float4*)s, x1 = *(const float4*)(s + 4);
                ushort8v h, l;
                bfpair p;
                p = split_bf16(x0.x); h[0] = p.h; l[0] = p.l;
                p = split_bf16(x0.y); h[1] = p.h; l[1] = p.l;
                p = split_bf16(x0.z); h[2] = p.h; l[2] = p.l;
                p = split_bf16(x0.w); h[3] = p.h; l[3] = p.l;
                p = split_bf16(x1.x); h[4] = p.h; l[4] = p.l;
                p = split_bf16(x1.y); h[5] = p.h; l[5] = p.l;
                p = split_bf16(x1.z); h[6] = p.h; l[6] = p.l;
                p = split_bf16(x1.w); h[7] = p.h; l[7] = p.l;
                *(ushort8v*)&Bh[row][c8] = h;
                *(ushort8v*)&Bl[row][c8] = l;
            }
        }
        __syncthreads();

        short8v ah[4], al[4], bh[4], bl[4];
#pragma unroll
        for (int ti = 0; ti < 4; ++ti) {
            ah[ti] = *(const short8v*)&Ah[wm * 64 + ti * 16 + fm][fq * 8];
            al[ti] = *(const short8v*)&Al[wm * 64 + ti * 16 + fm][fq * 8];
            bh[ti] = *(const short8v*)&Bh[wn * 64 + ti * 16 + fm][fq * 8];
            bl[ti] = *(const short8v*)&Bl[wn * 64 + ti * 16 + fm][fq * 8];
        }
#pragma unroll
        for (int ti = 0; ti < 4; ++ti)
#pragma unroll
            for (int tj = 0; tj < 4; ++tj) {
                acc[ti][tj] = __builtin_amdgcn_mfma_f32_16x16x32_bf16(
                    ah[ti], bh[tj], acc[ti][tj], 0, 0, 0);
                acc[ti][tj] = __builtin_amdgcn_mfma_f32_16x16x32_bf16(
                    ah[ti], bl[tj], acc[ti][tj], 0, 0, 0);
                acc[ti][tj] = __builtin_amdgcn_mfma_f32_16x16x32_bf16(
                    al[ti], bh[tj], acc[ti][tj], 0, 0, 0);
            }
    }

#pragma unroll
    for (int ti = 0; ti < 4; ++ti)
#pragma unroll
        for (int tj = 0; tj < 4; ++tj)
#pragma unroll
            for (int r = 0; r < 4; ++r) {
                const int row = m0 + wm * 64 + ti * 16 + fq * 4 + r;
                const int col = n0 + wn * 64 + tj * 16 + fm;
                O[(size_t)row * Cn + col] = acc[ti][tj][r];
            }
}

// ---------------------------------------------------------------------------
// Feature sparsify for Q and V (in place): per 64-elem head vector keep
// |v| >= 8th-largest |v|.  One wave per vector; 2*65536 vectors.
// ---------------------------------------------------------------------------
__global__ __launch_bounds__(256)
void sparsify_topk(float* __restrict__ Q, float* __restrict__ V)
{
    const int wid  = (blockIdx.x * 256 + threadIdx.x) >> 6;  // global wave id
    const int lane = threadIdx.x & 63;
    const int tensor = wid >> 16;        // 0=Q, 1=V
    const int vec    = wid & 65535;
    float* base = tensor ? V : Q;

    const size_t off = (size_t)vec * 64 + lane;
    const float v = base[off];
    const float a = fabsf(v);

    int cnt = 0;   // # strictly greater than mine
#pragma unroll
    for (int j = 0; j < 64; ++j) {
        const float aj = __shfl(a, j);
        cnt += (aj > a) ? 1 : 0;
    }
    float cand = (cnt < FKEEP) ? a : 3.402823466e38f;
#pragma unroll
    for (int o = 32; o; o >>= 1) cand = fminf(cand, __shfl_xor(cand, o));
    base[off] = (a >= cand) ? v : 0.0f;
}

// ---------------------------------------------------------------------------
// K sparsify + transpose: K[b][t][h][d] -> KT[bh][d][t] (both coalesced via
// a 64x64 LDS tile).  Same top-8 filter as sparsify_topk (identical fp32
// values -> attn scores bit-identical).  Grid (32 t-tiles, 32 bh).
// ---------------------------------------------------------------------------
__global__ __launch_bounds__(256)
void sparsify_k_t(const float* __restrict__ K, float* __restrict__ KT)
{
    __shared__ float tile[64][65];       // [t-row][d], pad 65

    const int tid = threadIdx.x;
    const int w = tid >> 6, lane = tid & 63;
    const int tt = blockIdx.x;           // t-tile 0..31
    const int bh = blockIdx.y;           // 0..31
    const int b = bh >> 4, h = bh & 15;
    const int t0 = tt * 64;

    // load 64 t-rows x 64 d, coalesced (each row = 256 B contiguous)
#pragma unroll
    for (int k = 0; k < 4; ++k) {
        const int c = tid + k * 256;     // 0..1023 float4-chunks
        const int row = c >> 4, off = (c & 15) * 4;
        const float4 v4 = *(const float4*)
            &K[(size_t)((b * Tn + t0 + row) * 16 + h) * 64 + off];
        tile[row][off + 0] = v4.x; tile[row][off + 1] = v4.y;
        tile[row][off + 2] = v4.z; tile[row][off + 3] = v4.w;
    }
    __syncthreads();

    // per-wave top-8 on t-rows w, w+4, ... (vector over d = lane)
#pragma unroll 1
    for (int r = w; r < 64; r += 4) {
        const float v = tile[r][lane];
        const float a = fabsf(v);
        int cnt = 0;
#pragma unroll
        for (int j = 0; j < 64; ++j) {
            const float aj = __shfl(a, j);
            cnt += (aj > a) ? 1 : 0;
        }
        float cand = (cnt < FKEEP) ? a : 3.402823466e38f;
#pragma unroll
        for (int o = 32; o; o >>= 1) cand = fminf(cand, __shfl_xor(cand, o));
        tile[r][lane] = (a >= cand) ? v : 0.0f;
    }
    __syncthreads();

    // store transposed: KT[(bh*64+d)*2048 + t0+lane], coalesced over t
#pragma unroll
    for (int k = 0; k < 16; ++k) {
        const int d = w + k * 4;
        KT[(((size_t)bh * 64 + d) << 11) + t0 + lane] = tile[lane][d];
    }
}

// ---------------------------------------------------------------------------
// Attention core, R12.  (R11: barrier-free via KT; neutral — latency-bound
// with LDS-capped occupancy, so this round doubles per-wave MLP instead.)
//  - score: q features hoisted out of the j-loop (8 readlanes ONCE, SGPR
//    K-base pointers), 2 col-groups per iteration -> 16 loads in flight.
//  - softmax+compaction fused, NO p write-back; PV recomputes
//    exp(score - fm) from the intact score (identical input -> bit-exact).
//  - PV unrolled x8 (8 V loads in flight); acc add order unchanged.
// LDS (37888 B): sc[NW][2112] | hist/ct[NW][256] (wave-private rows).
// ---------------------------------------------------------------------------
__global__ __launch_bounds__(256, 4)
void attn_kernel(const float* __restrict__ Qm, const float* __restrict__ KTm,
                 const float* __restrict__ Vm, float* __restrict__ AO)
{
    extern __shared__ unsigned smem[];
    unsigned* sc   = smem;                   // NW*2112 words
    unsigned* hist = smem + NW * SC_ROW;     // NW*256 words (select + compact)

    const int tid  = threadIdx.x;
    const int w    = tid >> 6;
    const int lane = tid & 63;
    const int bh   = blockIdx.y;             // 0..31
    const int b    = bh >> 4;
    const int h    = bh & 15;
    const int t    = blockIdx.x * NW + w;
    const size_t rowoff = ((size_t)(b * Tn + t) << 10) + (h << 6);
    const size_t kvoff  = ((size_t)(b * Tn) << 10) + (h << 6);

    unsigned* myrow = sc + w * SC_ROW;
    const int lb = (lane >> 5) * 33 + (lane & 31);  // striped lane base

    // ---- init own score row (incl pads): wave-private, no barrier ----
#pragma unroll
    for (int i = 0; i < 33; ++i) myrow[i * 64 + lane] = U_NEG_INF;

    // ---- sparse q row in a register; nonzero feature mask (wave-uniform) ----
    const float q0  = Qm[rowoff + lane];
    const float qsc = q0 * 0.125f;                  // fold 1/sqrt(D)
    const unsigned long long nzm = __ballot(q0 != 0.0f);
    const int nnz = __popcll(nzm);                  // wave-uniform, ==8 a.s.

    const int nj = (t >> 6) + 1;             // visible 64-col groups
    const float* ktb = KTm + ((size_t)bh << 17);    // [d][t] slice

    unsigned rowmax = 0u;
    if (nnz == 8) {
        // hoist the 8 features ONCE (R11 redid ctz+readlane+addr per group)
        float mq[8]; const float* kp[8];
        {
            unsigned long long mm = nzm;
#pragma unroll
            for (int i = 0; i < 8; ++i) {
                const int m = (int)__builtin_ctzll(mm); mm &= mm - 1;
                mq[i] = rlf(qsc, m);
                kp[i] = ktb + ((size_t)m << 11);
            }
        }
        int j = 0;
        for (; j + 2 <= nj; j += 2) {        // 16 loads in flight
            const int col0 = (j << 6) + lane, col1 = col0 + 64;
            float s0 = 0.0f, s1 = 0.0f;
#pragma unroll
            for (int i = 0; i < 8; ++i) {
                s0 += mq[i] * kp[i][col0];
                s1 += mq[i] * kp[i][col1];
            }
            const unsigned v0 = (col0 <= t) ? umap(s0) : U_NEG_INF;
            const unsigned v1 = (col1 <= t) ? umap(s1) : U_NEG_INF;
            myrow[j * 66 + lb]       = v0;
            myrow[(j + 1) * 66 + lb] = v1;
            rowmax = (v0 > rowmax) ? v0 : rowmax;
            rowmax = (v1 > rowmax) ? v1 : rowmax;
        }
        if (j < nj) {
            const int col = (j << 6) + lane;
            float s = 0.0f;
#pragma unroll
            for (int i = 0; i < 8; ++i) s += mq[i] * kp[i][col];
            const unsigned val = (col <= t) ? umap(s) : U_NEG_INF;
            myrow[j * 66 + lb] = val;
            rowmax = (val > rowmax) ? val : rowmax;
        }
    } else {
        // generic fallback (magnitude ties -> nnz > 8): rare, wave-uniform
        for (int j = 0; j < nj; ++j) {
            const int col = (j << 6) + lane;
            float s = 0.0f;
            unsigned long long mm = nzm;
            while (mm) {
                const int m = (int)__builtin_ctzll(mm); mm &= mm - 1;
                s += rlf(qsc, m) * ktb[((size_t)m << 11) + col];
            }
            const unsigned val = (col <= t) ? umap(s) : U_NEG_INF;
            myrow[j * 66 + lb] = val;
            rowmax = (val > rowmax) ? val : rowmax;
        }
    }

#pragma unroll
    for (int o = 32; o; o >>= 1) {
        const unsigned m2 = __shfl_xor(rowmax, o);
        rowmax = (m2 > rowmax) ? m2 : rowmax;
    }
    const float fm = uunmap(rowmax);         // row max (finite: col 0 <= t)

    // ---- exact kth via radix-256 select over LDS (wave-local) ----
    unsigned cur = U_NEG_INF;                // rows t<256 keep everything
    if (t >= KKEEP) {
        unsigned* hrow = hist + w * 256;
        unsigned prefix = 0u, pmask = 0u;
        unsigned r = KKEEP;
#pragma unroll 1
        for (int level = 0; level < 4; ++level) {
            const int sh = 24 - 8 * level;
            hrow[lane] = 0; hrow[64 + lane] = 0; hrow[128 + lane] = 0; hrow[192 + lane] = 0;
            __asm__ volatile("s_waitcnt lgkmcnt(0)" ::: "memory");
#pragma unroll 1
            for (int j = 0; j < nj; ++j) {
                const int col = (j << 6) + lane;
                if (col <= t) {
                    const unsigned v = myrow[j * 66 + lb];
                    if ((v & pmask) == prefix)
                        atomicAdd(&hrow[(v >> sh) & 255u], 1u);
                }
            }
            __asm__ volatile("s_waitcnt lgkmcnt(0)" ::: "memory");
            const uint4 hv = *(const uint4*)&hrow[lane * 4];   // bins 4l..4l+3
            const unsigned ls = hv.x + hv.y + hv.z + hv.w;
            unsigned sfx = ls;                    // inclusive suffix over lanes
#pragma unroll
            for (int off = 1; off < 64; off <<= 1) {
                const unsigned tt2 = __shfl_down(sfx, off);
                if (lane + off < 64) sfx += tt2;
            }
            const unsigned excl = sfx - ls;       // lanes strictly above
            const unsigned c3 = excl + hv.w, c2 = c3 + hv.z,
                           c1 = c2 + hv.y,  c0 = c1 + hv.x;
            int bsel = -1; unsigned csel = 0, cnext = 0;
            if      (c3 >= r) { bsel = 4 * lane + 3; csel = c3; cnext = excl; }
            else if (c2 >= r) { bsel = 4 * lane + 2; csel = c2; cnext = c3; }
            else if (c1 >= r) { bsel = 4 * lane + 1; csel = c1; cnext = c2; }
            else if (c0 >= r) { bsel = 4 * lane + 0; csel = c0; cnext = c1; }
            int B = bsel;
#pragma unroll
            for (int off = 32; off; off >>= 1) {
                const int ob = __shfl_xor(B, off);
                B = (ob > B) ? ob : B;
            }
            const unsigned cB  = (unsigned)__shfl((int)csel,  B >> 2);
            const unsigned cB1 = (unsigned)__shfl((int)cnext, B >> 2);
            prefix |= (unsigned)B << sh;
            pmask  |= 255u << sh;
            if (cB == r || level == 3) { cur = prefix; break; }
            r -= cB1;                    // rank within bin B
        }
    }

    // ---- FUSED softmax + compaction (single pass; no p write-back) ----
    unsigned* ct = hist + w * 256;       // own row only: no cross-wave hazard
    float ps = 0.0f;
    int cnt = 0; bool ovf = false;
#pragma unroll 1
    for (int j = 0; j < nj; ++j) {
        const int col = (j << 6) + lane;
        float pv = 0.0f;
        if (col <= t) {
            const unsigned uv = myrow[j * 66 + lb];
            if (uv >= cur) pv = __expf(uunmap(uv) - fm);
        }
        ps += pv;
        const unsigned long long m = __ballot(pv > 0.0f);
        const int c = __popcll(m);
        if (cnt + c <= 256) {
            if (pv > 0.0f)
                ct[cnt + __popcll(m & ((1ull << lane) - 1ull))] = (unsigned)col;
        } else ovf = true;
        cnt += c;
    }
#pragma unroll
    for (int o = 32; o; o >>= 1) ps += __shfl_xor(ps, o);
    const float inv = 1.0f / ps;         // ps >= 1 (row max is kept)

    float acc = 0.0f;
    const float* __restrict__ vcol = Vm + kvoff + lane;
    if (!ovf) {
        // lane l holds list entries blk*64+l; entries >= cnt: c=0, p=0.
        // p recomputed from the intact score — identical exp input as the
        // softmax pass -> bit-exact.
        int   cR[4]; float pR[4];
#pragma unroll
        for (int blk = 0; blk < 4; ++blk) {
            const int idx = blk * 64 + lane;
            cR[blk] = (idx < cnt) ? (int)ct[idx] : 0;
            pR[blk] = (idx < cnt)
                ? __expf(uunmap(myrow[sc_addr(cR[blk])]) - fm) : 0.0f;
        }
        // Broadcast via readlane (SALU); 8 independent loads per group.
        // NOTE: blk_p MUST be float (R9: `int blk_p` truncated all p to 0).
        auto do_blk = [&](int blk_c, float blk_p) {
#pragma unroll
            for (int j = 0; j < 64; j += 8) {
                const int   c0 = rli(blk_c, j + 0), c1 = rli(blk_c, j + 1);
                const int   c2 = rli(blk_c, j + 2), c3 = rli(blk_c, j + 3);
                const int   c4 = rli(blk_c, j + 4), c5 = rli(blk_c, j + 5);
                const int   c6 = rli(blk_c, j + 6), c7 = rli(blk_c, j + 7);
                const float p0 = rlf(blk_p, j + 0), p1 = rlf(blk_p, j + 1);
                const float p2 = rlf(blk_p, j + 2), p3 = rlf(blk_p, j + 3);
                const float p4 = rlf(blk_p, j + 4), p5 = rlf(blk_p, j + 5);
                const float p6 = rlf(blk_p, j + 6), p7 = rlf(blk_p, j + 7);
                const float v0 = vcol[(size_t)c0 * Cn], v1 = vcol[(size_t)c1 * Cn];
                const float v2 = vcol[(size_t)c2 * Cn], v3 = vcol[(size_t)c3 * Cn];
                const float v4 = vcol[(size_t)c4 * Cn], v5 = vcol[(size_t)c5 * Cn];
                const float v6 = vcol[(size_t)c6 * Cn], v7 = vcol[(size_t)c7 * Cn];
                acc += p0 * v0; acc += p1 * v1; acc += p2 * v2; acc += p3 * v3;
                acc += p4 * v4; acc += p5 * v5; acc += p6 * v6; acc += p7 * v7;
            }
        };
        do_blk(cR[0], pR[0]);
        if (cnt > 64)  do_blk(cR[1], pR[1]);
        if (cnt > 128) do_blk(cR[2], pR[2]);
        if (cnt > 192) do_blk(cR[3], pR[3]);
    } else {
        // tie-overflow fallback (rare): while(ballot) gather, p recomputed
#pragma unroll 1
        for (int g = 0; g < nj; ++g) {
            const int col = (g << 6) + lane;
            float pv = 0.0f;
            if (col <= t) {
                const unsigned uv = myrow[g * 66 + lb];
                if (uv >= cur) pv = __expf(uunmap(uv) - fm);
            }
            unsigned long long m = __ballot(pv > 0.0f);
            const int cb = g << 6;
            while (m) {
                const int l0 = __builtin_ctzll(m); m &= m - 1;
                const float w0 = __shfl(pv, l0);
                const float v0 = vcol[(size_t)(cb + l0) * Cn];
                float w1 = 0.0f, v1 = 0.0f;
                if (m) {
                    const int l1 = __builtin_ctzll(m); m &= m - 1;
                    w1 = __shfl(pv, l1);
                    v1 = vcol[(size_t)(cb + l1) * Cn];
                }
                acc += w0 * v0;
                acc += w1 * v1;
            }
        }
    }
    AO[rowoff + lane] = acc * inv;
}

// ---------------------------------------------------------------------------
extern "C" void kernel_launch(void* const* d_in, const int* in_sizes, int n_in,
                              void* d_out, int out_size, void* d_ws, size_t ws_size,
                              hipStream_t stream)
{
    const float* x  = (const float*)d_in[0];
    const float* Wq = (const float*)d_in[1];
    const float* Wk = (const float*)d_in[2];
    const float* Wv = (const float*)d_in[3];
    const float* Wo = (const float*)d_in[4];
    float* out = (float*)d_out;

    // 4 x 16.8 MB workspace buffers:
    //   buf0=Q, buf1=K-dense (dead after transpose; reused as AO),
    //   buf2=V, buf3=KT.
    float* Q  = (float*)d_ws;
    float* K  = Q + (size_t)Mn * Cn;
    float* V  = K + (size_t)Mn * Cn;
    float* KT = V + (size_t)Mn * Cn;
    float* AO = K;                       // alias: K-dense dead after step 3

    constexpr int ATTN_LDS = NW * (SC_ROW + 256) * 4;    // 37888 B
    static_assert(ATTN_LDS <= 65536, "LDS over default dynamic cap");

    // 1) Q/K/V projections (split-bf16 MFMA, ~fp32 accuracy)
    gemm_nt_3bf16<<<dim3(Cn / 128, Mn / 128, 3), 256, 0, stream>>>(
        x, Wq, Wk, Wv, Q, K, V);

    // 2) feature top-8 sparsification of Q and V, in place
    sparsify_topk<<<dim3(2 * 65536 / 4), 256, 0, stream>>>(Q, V);

    // 3) K sparsify + transpose -> KT[bh][d][t]
    sparsify_k_t<<<dim3(32, 32), 256, 0, stream>>>(K, KT);

    // 4) barrier-free sparse attention core -> AO in [B,T,C] layout
    attn_kernel<<<dim3(Tn / NW, 32), 256, ATTN_LDS, stream>>>(Q, KT, V, AO);

    // 5) output projection (split-bf16 MFMA)
    gemm_nt_3bf16<<<dim3(Cn / 128, Mn / 128, 1), 256, 0, stream>>>(
        AO, Wo, Wo, Wo, out, out, out);
}